// Round 12
// baseline (4578.805 us; speedup 1.0000x reference)
//
#include <hip/hip_runtime.h>

// Residual VQ on MI355X (gfx950) — MFMA distance engine, one-sweep + exact rescue.
// z: [8, 32768, 32] f32; codebooks: [10, 512, 32] f32.
// Outputs (flat f32 in d_out): quantized [B,N,D], indices [B,N,Q] (as float),
// commit_loss [Q] (zeros).
//
// R12 = R11 (bf16 2-term split MFMA distances, exact-rescue, replay kernel,
// no d_ws) restructured to ONE sweep: R11 spent ~95% of wall serialized
// (MfmaUtil 13%, VALUBusy 21%, 18 syncs/stage, candidates staged+converted
// twice, sweep2 re-ran all MFMAs). Key insight: sweep-1's per-lane running
// min IS a per-(point, candidate-class mod 16) min — free pruning info.
//   sweep (MFMA): runmin[tile][i] accumulates min of d_approx per class.
//   classmin LDS [128][16] (pad 17): per point per class min.
//   R phase: thr = min_class + (rr+ccmax)*2^-9 (error bound (rr+cc)*2^-12.4);
//     exact-eval (reference fp32 tree) all cands of admitted classes;
//     winner = (min d_ref, lowest idx)  -> reference argmin EXACTLY
//     (argmin_ref's class always admitted; superset-eval is order-safe).
// Norms folded into staging (snorm from the staged vector, exact tree).
// Distance/update arithmetic bit-identical to the proven chain (absmax 0.0
// in R1/R3-R11). quantized rebuilt by the proven replay kernel.

#define RVQ_Q 10
#define RVQ_C 512
#define RVQ_D 32

static constexpr int  NPTS     = 262144;
static constexpr long IDX_OFF  = (long)NPTS * RVQ_D;
static constexpr long LOSS_OFF = IDX_OFF + (long)NPTS * RVQ_Q;
static constexpr int  BPTS     = 128;   // points per search block
static constexpr int  QC       = 128;   // candidates per staged quarter

typedef __attribute__((ext_vector_type(32))) float f32x32;
typedef __attribute__((ext_vector_type(8)))  short short8;
typedef __attribute__((ext_vector_type(4)))  float f32x4;

// ---------------------------------------------------------------------------
// reference-exact numpy reduction tree (proven absmax 0.0 in R1/R3-R11)
__device__ __forceinline__ float tree_dot(const f32x32& x, const f32x32& y) {
    float a[8];
#pragma unroll
    for (int j = 0; j < 8; ++j) a[j] = x[j] * y[j];
#pragma unroll
    for (int j = 8; j < RVQ_D; ++j) a[j & 7] = fmaf(x[j], y[j], a[j & 7]);
    return ((a[0] + a[1]) + (a[2] + a[3])) + ((a[4] + a[5]) + (a[6] + a[7]));
}

// bit-exact straight-through residual update
__device__ __forceinline__ f32x32 st_update(const f32x32& r, const f32x32& gv) {
    const f32x32 tt  = gv - r;
    const f32x32 qst = r + tt;
    return r - qst;
}

__device__ __forceinline__ short8 as_s8(uint4 u) {
    union { uint4 a; short8 b; } x; x.a = u; return x.b;
}

// pack two floats' bf16-truncations into one u32 (lo = v0, hi = v1)
__device__ __forceinline__ unsigned pk_hi(float v0, float v1) {
    return (__float_as_uint(v0) >> 16) | (__float_as_uint(v1) & 0xFFFF0000u);
}
__device__ __forceinline__ float lo_rem(float v) {  // v - bf16_trunc(v)
    return v - __uint_as_float(__float_as_uint(v) & 0xFFFF0000u);
}

// ---------------------------------------------------------------------------
__global__ __launch_bounds__(128, 2) void rvq_search(const float* __restrict__ z,
                                                     const float* __restrict__ cb,
                                                     float* __restrict__ out) {
    __shared__ uint4 ptfrag[BPTS * 8];        // 16 KB  point bf16 splits (-2r)
    __shared__ uint4 cfrag[QC * 8];           // 16 KB  candidate bf16 splits
    __shared__ float snorm[RVQ_C];            // 2 KB   exact-tree norms
    __shared__ float rrbuf[BPTS];             // 0.5 KB
    __shared__ float classmin[BPTS * 17];     // 8.7 KB (pad 17 vs bank conflicts)
    __shared__ int ccmax_i;

    const int t    = threadIdx.x;
    const int lane = t & 63;
    const int w    = t >> 6;        // wave 0/1
    const int col  = lane & 15;
    const int g    = lane >> 4;
    const int sw0  = g ^ (col & 7);        // swizzled chunk idx, split 0
    const int sw1  = (4 + g) ^ (col & 7);  // split 1
    const long p   = (long)blockIdx.x * BPTS + t;

    f32x32 r = *(const f32x32*)(z + p * RVQ_D);

#pragma unroll 1
    for (int q = 0; q < RVQ_Q; ++q) {
        const float* cbq = cb + (long)q * RVQ_C * RVQ_D;
        __syncthreads();   // S0: prev stage's R-phase LDS reads done

        // ---- E phase: rr, -2r bf16 split -> ptfrag, ccmax reset
        const float rr = tree_dot(r, r);
        rrbuf[t] = rr;
        if (t == 0) ccmax_i = 0;
        {
            const f32x32 s = -2.0f * r;
#pragma unroll
            for (int sp = 0; sp < 2; ++sp)
#pragma unroll
                for (int gg = 0; gg < 4; ++gg) {
                    unsigned u[4];
#pragma unroll
                    for (int pr = 0; pr < 4; ++pr) {
                        const int j = gg * 8 + pr * 2;
                        float v0 = s[j], v1 = s[j + 1];
                        if (sp == 1) { v0 = lo_rem(v0); v1 = lo_rem(v1); }
                        u[pr] = pk_hi(v0, v1);
                    }
                    ptfrag[t * 8 + ((sp * 4 + gg) ^ (t & 7))] =
                        make_uint4(u[0], u[1], u[2], u[3]);
                }
        }
        __syncthreads();   // SE: E writes visible; ccmax reset before atomics

        // ============ single sweep: per-(point,class) min of d_approx ======
        float runmin[4][4];
#pragma unroll
        for (int a = 0; a < 4; ++a)
#pragma unroll
            for (int b = 0; b < 4; ++b) runmin[a][b] = __builtin_inff();

#pragma unroll 1
        for (int qr = 0; qr < 4; ++qr) {
            if (qr > 0) __syncthreads();   // prev quarter's cfrag readers done
            {   // stage candidate quarter + norms (exact tree) + ccmax
                const f32x32 c = *(const f32x32*)(cbq + (long)(qr * QC + t) * RVQ_D);
                const float cc = tree_dot(c, c);
                snorm[qr * QC + t] = cc;
                atomicMax(&ccmax_i, __float_as_int(cc));
#pragma unroll
                for (int sp = 0; sp < 2; ++sp)
#pragma unroll
                    for (int gg = 0; gg < 4; ++gg) {
                        unsigned u[4];
#pragma unroll
                        for (int pr = 0; pr < 4; ++pr) {
                            const int j = gg * 8 + pr * 2;
                            float v0 = c[j], v1 = c[j + 1];
                            if (sp == 1) { v0 = lo_rem(v0); v1 = lo_rem(v1); }
                            u[pr] = pk_hi(v0, v1);
                        }
                        cfrag[t * 8 + ((sp * 4 + gg) ^ (t & 7))] =
                            make_uint4(u[0], u[1], u[2], u[3]);
                    }
            }
            __syncthreads();

#pragma unroll 1
            for (int dual = 0; dual < 2; ++dual) {
                const int TA = w * 4 + dual * 2;        // block tile ids
                const int ptA = TA * 16 + col, ptB = (TA + 1) * 16 + col;
                const short8 ahA = as_s8(ptfrag[ptA * 8 + sw0]);
                const short8 alA = as_s8(ptfrag[ptA * 8 + sw1]);
                const short8 ahB = as_s8(ptfrag[ptB * 8 + sw0]);
                const short8 alB = as_s8(ptfrag[ptB * 8 + sw1]);
                float rrA[4], rrB[4];
#pragma unroll
                for (int i = 0; i < 4; ++i) {
                    rrA[i] = rrbuf[TA * 16 + 4 * g + i];
                    rrB[i] = rrbuf[(TA + 1) * 16 + 4 * g + i];
                }
#pragma unroll 2
                for (int ct = 0; ct < 8; ++ct) {
                    const int cl_ = ct * 16 + col;
                    const short8 bh = as_s8(cfrag[cl_ * 8 + sw0]);
                    const short8 bl = as_s8(cfrag[cl_ * 8 + sw1]);
                    const float ccv = snorm[qr * QC + cl_];
                    f32x4 acc = {rrA[0] + ccv, rrA[1] + ccv, rrA[2] + ccv, rrA[3] + ccv};
                    acc = __builtin_amdgcn_mfma_f32_16x16x32_bf16(ahA, bh, acc, 0, 0, 0);
                    acc = __builtin_amdgcn_mfma_f32_16x16x32_bf16(alA, bh, acc, 0, 0, 0);
                    acc = __builtin_amdgcn_mfma_f32_16x16x32_bf16(ahA, bl, acc, 0, 0, 0);
#pragma unroll
                    for (int i = 0; i < 4; ++i)
                        runmin[dual * 2][i] = fminf(runmin[dual * 2][i], acc[i]);
                    f32x4 acc2 = {rrB[0] + ccv, rrB[1] + ccv, rrB[2] + ccv, rrB[3] + ccv};
                    acc2 = __builtin_amdgcn_mfma_f32_16x16x32_bf16(ahB, bh, acc2, 0, 0, 0);
                    acc2 = __builtin_amdgcn_mfma_f32_16x16x32_bf16(alB, bh, acc2, 0, 0, 0);
                    acc2 = __builtin_amdgcn_mfma_f32_16x16x32_bf16(ahB, bl, acc2, 0, 0, 0);
#pragma unroll
                    for (int i = 0; i < 4; ++i)
                        runmin[dual * 2 + 1][i] = fminf(runmin[dual * 2 + 1][i], acc2[i]);
                }
            }
        }

        // ---- publish per-(point, class) minima
#pragma unroll
        for (int tl = 0; tl < 4; ++tl)
#pragma unroll
            for (int i = 0; i < 4; ++i)
                classmin[((w * 4 + tl) * 16 + 4 * g + i) * 17 + col] = runmin[tl][i];
        __syncthreads();   // S3: classmin + ccmax + all snorm visible

        // ---- R phase: exact shortlist eval over admitted classes
        {
            const float ccm = __int_as_float(ccmax_i);
            float m = __builtin_inff();
#pragma unroll
            for (int c = 0; c < 16; ++c) m = fminf(m, classmin[t * 17 + c]);
            const float thr = m + (rr + ccm) * 0.001953125f;   // 2^-9
            float bd = __builtin_inff(); int bi = 0;
#pragma unroll 1
            for (int c = 0; c < 16; ++c) {
                if (classmin[t * 17 + c] <= thr) {
#pragma unroll 1
                    for (int kk = 0; kk < 32; ++kk) {
                        const int cnd = kk * 16 + c;
                        const f32x32 cvv = *(const f32x32*)(cbq + (long)cnd * RVQ_D);
                        const float d = fmaf(-2.0f, tree_dot(r, cvv), rr) + snorm[cnd];
                        if (d < bd || (d == bd && cnd < bi)) { bd = d; bi = cnd; }
                    }
                }
            }
            out[IDX_OFF + p * RVQ_Q + q] = (float)bi;
            const f32x32 gw = *(const f32x32*)(cbq + (long)bi * RVQ_D);
            r = st_update(r, gw);
        }
    }
}

// ---------------------------------------------------------------------------
// Replay: bit-exact straight-through chain from stored indices (proven
// pre+post-timing R3-R11). Writes quantized + commit_loss.
__global__ __launch_bounds__(256) void rvq_replay(const float* __restrict__ z,
                                                  const float* __restrict__ cb,
                                                  float* __restrict__ out) {
    const int p = blockIdx.x * 256 + threadIdx.x;

    float r[RVQ_D], oacc[RVQ_D];
    {
        const float4* zp = (const float4*)(z + (long)p * RVQ_D);
#pragma unroll
        for (int w = 0; w < 8; ++w) {
            const float4 v = zp[w];
            r[w * 4 + 0] = v.x; r[w * 4 + 1] = v.y;
            r[w * 4 + 2] = v.z; r[w * 4 + 3] = v.w;
        }
    }
#pragma unroll
    for (int d = 0; d < RVQ_D; ++d) oacc[d] = 0.0f;

#pragma unroll 1
    for (int q = 0; q < RVQ_Q; ++q) {
        const int idx = (int)out[IDX_OFF + (long)p * RVQ_Q + q];
        const float4* cwb = (const float4*)(cb + ((long)q * RVQ_C + idx) * RVQ_D);
        float cwv[RVQ_D];
#pragma unroll
        for (int w = 0; w < 8; ++w) {
            const float4 v = cwb[w];
            cwv[w * 4 + 0] = v.x; cwv[w * 4 + 1] = v.y;
            cwv[w * 4 + 2] = v.z; cwv[w * 4 + 3] = v.w;
        }
#pragma unroll
        for (int d = 0; d < RVQ_D; ++d) {
            const float qst = r[d] + (cwv[d] - r[d]);
            oacc[d] += qst;
            r[d] = r[d] - qst;
        }
    }

    float4* qo = (float4*)(out + (long)p * RVQ_D);
#pragma unroll
    for (int w = 0; w < 8; ++w) {
        float4 v;
        v.x = oacc[w * 4 + 0]; v.y = oacc[w * 4 + 1];
        v.z = oacc[w * 4 + 2]; v.w = oacc[w * 4 + 3];
        qo[w] = v;
    }

    if (p < RVQ_Q) out[LOSS_OFF + p] = 0.0f;
}

// ---------------------------------------------------------------------------
extern "C" void kernel_launch(void* const* d_in, const int* in_sizes, int n_in,
                              void* d_out, int out_size, void* d_ws, size_t ws_size,
                              hipStream_t stream) {
    const float* z  = (const float*)d_in[0];
    const float* cb = (const float*)d_in[1];
    float* out = (float*)d_out;
    (void)d_ws; (void)ws_size;   // no workspace (R6 lesson)

    rvq_search<<<NPTS / BPTS, BPTS, 0, stream>>>(z, cb, out);
    rvq_replay<<<NPTS / 256, 256, 0, stream>>>(z, cb, out);
}

// Round 13
// 1591.649 us; speedup vs baseline: 2.8768x; 2.8768x over previous
//
#include <hip/hip_runtime.h>
#include <hip/hip_fp16.h>

// Residual VQ on MI355X (gfx950) — one-sweep MFMA distance engine with
// per-class (min, argmin, 2nd-min) tracking + exact rescue.
// z: [8, 32768, 32] f32; codebooks: [10, 512, 32] f32.
// Outputs (flat f32 in d_out): quantized [B,N,D], indices [B,N,Q] (as float),
// commit_loss [Q] (zeros).
//
// R13 = R11's proven MFMA core (bf16 2-term split, |d3-d_ref| <=
// (rr+cc)*2^-13.4; mapping validated by R11 absmax 0.0) with ONE sweep:
// track per (point, class=cand mod 16): m1 = min d3, id = argmin cand,
// m2 = 2nd min. R phase: thr = min_c m1 + (rr+ccmax)*2^-9; admitted class
// -> exact-eval id only; if m2 <= thr -> full 32-cand class scan (rare).
// Exact: ref-argmin's class always admitted (2err << delta); if it isn't
// the class d3-argmin it bounds m2 <= thr -> scanned; ties within window.
// R12's failure (>=32 exact evals/pt) fixed back to E[~1.05].
// m1/m2 stored as round-DOWN fp16 (conservative; granularity <= delta/2)
// -> LDS 47 KB -> 3 blocks/CU. Exact eval/update arithmetic bit-identical
// to the proven chain (absmax 0.0 R1/R3-R12). No d_ws (R6 lesson).

#define RVQ_Q 10
#define RVQ_C 512
#define RVQ_D 32

static constexpr int  NPTS     = 262144;
static constexpr long IDX_OFF  = (long)NPTS * RVQ_D;
static constexpr long LOSS_OFF = IDX_OFF + (long)NPTS * RVQ_Q;
static constexpr int  BPTS     = 128;   // points per search block
static constexpr int  QC       = 128;   // candidates per staged quarter

typedef __attribute__((ext_vector_type(32))) float f32x32;
typedef __attribute__((ext_vector_type(8)))  short short8;
typedef __attribute__((ext_vector_type(4)))  float f32x4;

// ---------------------------------------------------------------------------
// reference-exact numpy reduction tree (proven absmax 0.0 in R1/R3-R12)
__device__ __forceinline__ float tree_dot(const f32x32& x, const f32x32& y) {
    float a[8];
#pragma unroll
    for (int j = 0; j < 8; ++j) a[j] = x[j] * y[j];
#pragma unroll
    for (int j = 8; j < RVQ_D; ++j) a[j & 7] = fmaf(x[j], y[j], a[j & 7]);
    return ((a[0] + a[1]) + (a[2] + a[3])) + ((a[4] + a[5]) + (a[6] + a[7]));
}

__device__ __forceinline__ f32x32 st_update(const f32x32& r, const f32x32& gv) {
    const f32x32 tt  = gv - r;
    const f32x32 qst = r + tt;
    return r - qst;
}

__device__ __forceinline__ short8 as_s8(uint4 u) {
    union { uint4 a; short8 b; } x; x.a = u; return x.b;
}
__device__ __forceinline__ unsigned pk_hi(float v0, float v1) {
    return (__float_as_uint(v0) >> 16) | (__float_as_uint(v1) & 0xFFFF0000u);
}
__device__ __forceinline__ float lo_rem(float v) {
    return v - __uint_as_float(__float_as_uint(v) & 0xFFFF0000u);
}
// round-down fp16 pair pack (conservative: stored <= actual)
__device__ __forceinline__ unsigned pack_mm(float m1, float m2) {
    const unsigned a = __half_as_ushort(__float2half_rd(m1));
    const unsigned b = __half_as_ushort(__float2half_rd(m2));
    return a | (b << 16);
}
__device__ __forceinline__ float unpk_lo(unsigned u) {
    return __half2float(__ushort_as_half((unsigned short)(u & 0xFFFFu)));
}
__device__ __forceinline__ float unpk_hi(unsigned u) {
    return __half2float(__ushort_as_half((unsigned short)(u >> 16)));
}

// ---------------------------------------------------------------------------
__global__ __launch_bounds__(128, 2) void rvq_search(const float* __restrict__ z,
                                                     const float* __restrict__ cb,
                                                     float* __restrict__ out) {
    __shared__ uint4 ptfrag[BPTS * 8];            // 16 KB point bf16 splits (-2r)
    __shared__ uint4 cfrag[QC * 8];               // 16 KB candidate bf16 splits
    __shared__ float snorm[RVQ_C];                // 2 KB exact-tree norms
    __shared__ float rrbuf[BPTS];                 // 0.5 KB
    __shared__ unsigned classmm[BPTS * 17];       // 8.5 KB (m1|m2 fp16-rd pair)
    __shared__ unsigned short classid[BPTS * 16]; // 4 KB
    __shared__ int ccmax_i;

    const int t    = threadIdx.x;
    const int lane = t & 63;
    const int w    = t >> 6;        // wave 0/1
    const int col  = lane & 15;
    const int g    = lane >> 4;
    const int sw0  = g ^ (col & 7);
    const int sw1  = (4 + g) ^ (col & 7);
    const long p   = (long)blockIdx.x * BPTS + t;

    f32x32 r = *(const f32x32*)(z + p * RVQ_D);

#pragma unroll 1
    for (int q = 0; q < RVQ_Q; ++q) {
        const float* cbq = cb + (long)q * RVQ_C * RVQ_D;
        __syncthreads();   // S0: prev stage's R-phase LDS reads done

        // ---- E phase: rr, -2r bf16 split -> ptfrag, ccmax reset
        const float rr = tree_dot(r, r);
        rrbuf[t] = rr;
        if (t == 0) ccmax_i = 0;
        {
            const f32x32 s = -2.0f * r;
#pragma unroll
            for (int sp = 0; sp < 2; ++sp)
#pragma unroll
                for (int gg = 0; gg < 4; ++gg) {
                    unsigned u[4];
#pragma unroll
                    for (int pr = 0; pr < 4; ++pr) {
                        const int j = gg * 8 + pr * 2;
                        float v0 = s[j], v1 = s[j + 1];
                        if (sp == 1) { v0 = lo_rem(v0); v1 = lo_rem(v1); }
                        u[pr] = pk_hi(v0, v1);
                    }
                    ptfrag[t * 8 + ((sp * 4 + gg) ^ (t & 7))] =
                        make_uint4(u[0], u[1], u[2], u[3]);
                }
        }
        __syncthreads();   // SE

        // ---- per-(point,class) trackers: m1, m2, id (all SSA-indexed)
        float m1[4][4], m2[4][4];
        int   idr[4][4];
#pragma unroll
        for (int a = 0; a < 4; ++a)
#pragma unroll
            for (int b = 0; b < 4; ++b) {
                m1[a][b] = __builtin_inff(); m2[a][b] = __builtin_inff();
                idr[a][b] = 0;
            }

#pragma unroll 1
        for (int qr = 0; qr < 4; ++qr) {
            {   // stage candidate quarter + norms + ccmax (wave-reduced)
                const f32x32 c = *(const f32x32*)(cbq + (long)(qr * QC + t) * RVQ_D);
                const float cc = tree_dot(c, c);
                snorm[qr * QC + t] = cc;
                float cm = cc;
#pragma unroll
                for (int m_ = 1; m_ <= 32; m_ <<= 1) cm = fmaxf(cm, __shfl_xor(cm, m_, 64));
                if (lane == 0) atomicMax(&ccmax_i, __float_as_int(cm));
#pragma unroll
                for (int sp = 0; sp < 2; ++sp)
#pragma unroll
                    for (int gg = 0; gg < 4; ++gg) {
                        unsigned u[4];
#pragma unroll
                        for (int pr = 0; pr < 4; ++pr) {
                            const int j = gg * 8 + pr * 2;
                            float v0 = c[j], v1 = c[j + 1];
                            if (sp == 1) { v0 = lo_rem(v0); v1 = lo_rem(v1); }
                            u[pr] = pk_hi(v0, v1);
                        }
                        cfrag[t * 8 + ((sp * 4 + gg) ^ (t & 7))] =
                            make_uint4(u[0], u[1], u[2], u[3]);
                    }
            }
            __syncthreads();   // SYNC_A: cfrag/snorm ready

#pragma unroll 1
            for (int dual = 0; dual < 2; ++dual) {
                const int TA = w * 4 + dual * 2;
                const int ptA = TA * 16 + col, ptB = (TA + 1) * 16 + col;
                const short8 ahA = as_s8(ptfrag[ptA * 8 + sw0]);
                const short8 alA = as_s8(ptfrag[ptA * 8 + sw1]);
                const short8 ahB = as_s8(ptfrag[ptB * 8 + sw0]);
                const short8 alB = as_s8(ptfrag[ptB * 8 + sw1]);
                float rrA[4], rrB[4];
#pragma unroll
                for (int i = 0; i < 4; ++i) {
                    rrA[i] = rrbuf[TA * 16 + 4 * g + i];
                    rrB[i] = rrbuf[(TA + 1) * 16 + 4 * g + i];
                }
#pragma unroll 2
                for (int ct = 0; ct < 8; ++ct) {
                    const int cl_ = ct * 16 + col;
                    const short8 bh = as_s8(cfrag[cl_ * 8 + sw0]);
                    const short8 bl = as_s8(cfrag[cl_ * 8 + sw1]);
                    const float ccv = snorm[qr * QC + cl_];
                    const int   cnd = qr * QC + cl_;
                    f32x4 acc = {rrA[0] + ccv, rrA[1] + ccv, rrA[2] + ccv, rrA[3] + ccv};
                    acc = __builtin_amdgcn_mfma_f32_16x16x32_bf16(ahA, bh, acc, 0, 0, 0);
                    acc = __builtin_amdgcn_mfma_f32_16x16x32_bf16(alA, bh, acc, 0, 0, 0);
                    acc = __builtin_amdgcn_mfma_f32_16x16x32_bf16(ahA, bl, acc, 0, 0, 0);
#pragma unroll
                    for (int i = 0; i < 4; ++i) {
                        const float v = acc[i];
                        const int  tl = dual * 2;
                        const bool lt = v < m1[tl][i];
                        m2[tl][i]  = lt ? m1[tl][i] : fminf(m2[tl][i], v);
                        idr[tl][i] = lt ? cnd : idr[tl][i];
                        m1[tl][i]  = lt ? v : m1[tl][i];
                    }
                    f32x4 acc2 = {rrB[0] + ccv, rrB[1] + ccv, rrB[2] + ccv, rrB[3] + ccv};
                    acc2 = __builtin_amdgcn_mfma_f32_16x16x32_bf16(ahB, bh, acc2, 0, 0, 0);
                    acc2 = __builtin_amdgcn_mfma_f32_16x16x32_bf16(alB, bh, acc2, 0, 0, 0);
                    acc2 = __builtin_amdgcn_mfma_f32_16x16x32_bf16(ahB, bl, acc2, 0, 0, 0);
#pragma unroll
                    for (int i = 0; i < 4; ++i) {
                        const float v = acc2[i];
                        const int  tl = dual * 2 + 1;
                        const bool lt = v < m1[tl][i];
                        m2[tl][i]  = lt ? m1[tl][i] : fminf(m2[tl][i], v);
                        idr[tl][i] = lt ? cnd : idr[tl][i];
                        m1[tl][i]  = lt ? v : m1[tl][i];
                    }
                }
            }
            if (qr < 3) __syncthreads();   // SYNC_B: cfrag readers done
        }

        // ---- publish per-(point,class) trackers
#pragma unroll
        for (int tl = 0; tl < 4; ++tl)
#pragma unroll
            for (int i = 0; i < 4; ++i) {
                const int pt = (w * 4 + tl) * 16 + 4 * g + i;
                classmm[pt * 17 + col] = pack_mm(m1[tl][i], m2[tl][i]);
                classid[pt * 16 + col] = (unsigned short)idr[tl][i];
            }
        __syncthreads();   // SYNC_C: classmm/classid/ccmax visible

        // ---- R phase: exact eval of admitted class argmins (+rare full scans)
        {
            const float ccm = __int_as_float(ccmax_i);
            float mm = __builtin_inff();
#pragma unroll
            for (int c = 0; c < 16; ++c) mm = fminf(mm, unpk_lo(classmm[t * 17 + c]));
            const float thr = mm + (rr + ccm) * 0.001953125f;   // 2^-9

            float bd = __builtin_inff(); int bi = 0;
            auto evalExact = [&](int cnd) {
                const f32x32 cvv = *(const f32x32*)(cbq + (long)cnd * RVQ_D);
                const float d = fmaf(-2.0f, tree_dot(r, cvv), rr) + snorm[cnd];
                if (d < bd || (d == bd && cnd < bi)) { bd = d; bi = cnd; }
            };
#pragma unroll 1
            for (int c = 0; c < 16; ++c) {
                const unsigned u = classmm[t * 17 + c];
                if (unpk_lo(u) <= thr) {
                    if (unpk_hi(u) <= thr) {
#pragma unroll 1
                        for (int kk = 0; kk < 32; ++kk) evalExact(kk * 16 + c);
                    } else {
                        evalExact((int)classid[t * 16 + c]);
                    }
                }
            }
            out[IDX_OFF + p * RVQ_Q + q] = (float)bi;
            const f32x32 gw = *(const f32x32*)(cbq + (long)bi * RVQ_D);
            r = st_update(r, gw);
        }
    }
}

// ---------------------------------------------------------------------------
// Replay: bit-exact straight-through chain from stored indices (proven
// pre+post-timing R3-R12). Writes quantized + commit_loss.
__global__ __launch_bounds__(256) void rvq_replay(const float* __restrict__ z,
                                                  const float* __restrict__ cb,
                                                  float* __restrict__ out) {
    const int p = blockIdx.x * 256 + threadIdx.x;

    float r[RVQ_D], oacc[RVQ_D];
    {
        const float4* zp = (const float4*)(z + (long)p * RVQ_D);
#pragma unroll
        for (int w = 0; w < 8; ++w) {
            const float4 v = zp[w];
            r[w * 4 + 0] = v.x; r[w * 4 + 1] = v.y;
            r[w * 4 + 2] = v.z; r[w * 4 + 3] = v.w;
        }
    }
#pragma unroll
    for (int d = 0; d < RVQ_D; ++d) oacc[d] = 0.0f;

#pragma unroll 1
    for (int q = 0; q < RVQ_Q; ++q) {
        const int idx = (int)out[IDX_OFF + (long)p * RVQ_Q + q];
        const float4* cwb = (const float4*)(cb + ((long)q * RVQ_C + idx) * RVQ_D);
        float cwv[RVQ_D];
#pragma unroll
        for (int w = 0; w < 8; ++w) {
            const float4 v = cwb[w];
            cwv[w * 4 + 0] = v.x; cwv[w * 4 + 1] = v.y;
            cwv[w * 4 + 2] = v.z; cwv[w * 4 + 3] = v.w;
        }
#pragma unroll
        for (int d = 0; d < RVQ_D; ++d) {
            const float qst = r[d] + (cwv[d] - r[d]);
            oacc[d] += qst;
            r[d] = r[d] - qst;
        }
    }

    float4* qo = (float4*)(out + (long)p * RVQ_D);
#pragma unroll
    for (int w = 0; w < 8; ++w) {
        float4 v;
        v.x = oacc[w * 4 + 0]; v.y = oacc[w * 4 + 1];
        v.z = oacc[w * 4 + 2]; v.w = oacc[w * 4 + 3];
        qo[w] = v;
    }

    if (p < RVQ_Q) out[LOSS_OFF + p] = 0.0f;
}

// ---------------------------------------------------------------------------
extern "C" void kernel_launch(void* const* d_in, const int* in_sizes, int n_in,
                              void* d_out, int out_size, void* d_ws, size_t ws_size,
                              hipStream_t stream) {
    const float* z  = (const float*)d_in[0];
    const float* cb = (const float*)d_in[1];
    float* out = (float*)d_out;
    (void)d_ws; (void)ws_size;   // no workspace (R6 lesson)

    rvq_search<<<NPTS / BPTS, BPTS, 0, stream>>>(z, cb, out);
    rvq_replay<<<NPTS / 256, 256, 0, stream>>>(z, cb, out);
}

// Round 14
// 698.424 us; speedup vs baseline: 6.5559x; 2.2789x over previous
//
#include <hip/hip_runtime.h>
#include <hip/hip_fp16.h>

// Residual VQ on MI355X (gfx950) — MFMA distance engine, barrier-free search.
// z: [8, 32768, 32] f32; codebooks: [10, 512, 32] f32.
// Outputs (flat f32 in d_out): quantized [B,N,D], indices [B,N,Q] (as float),
// commit_loss [Q] (zeros).
//
// R14 = R13's proven math (bf16 2-term split MFMA distances, per-class
// m1/m2/id tracking, thr = min + (rr+ccmax)*2^-9 exact rescue — absmax 0.0)
// with the structure fixed: R7/R9/R11/R13 all converged at ~1600 us with
// both pipes <40% busy — the common sins were per-block codebook
// re-staging/re-conversion behind syncthreads pairs and 2 blocks/CU.
// Here: (1) prep kernel converts the codebook to MFMA-ready bf16 hi/lo
// fragments + exact norms ONCE into the quantized region of d_out (legal
// scratch: rewritten every call, replay overwrites it; d_ws unused per R6);
// (2) search uses 1-WAVE blocks (64 pts) — candidate fragments stream from
// L2 with ZERO barriers (single-wave LDS needs no syncthreads), compiler
// free to pipeline the loads; (3) LDS 48.6 -> 16.5 KB -> ~9 blocks/CU.
// Exact eval / straight-through update bit-identical to the proven chain.

#define RVQ_Q 10
#define RVQ_C 512
#define RVQ_D 32

static constexpr int  NPTS      = 262144;
static constexpr long IDX_OFF   = (long)NPTS * RVQ_D;
static constexpr long LOSS_OFF  = IDX_OFF + (long)NPTS * RVQ_Q;
static constexpr int  BPTS      = 64;            // points per block (1 wave)
static constexpr int  SCB_U4    = RVQ_Q * 32 * 8 * 16;   // 40960 uint4
static constexpr long NORM_OFF  = (long)SCB_U4 * 4;      // floats into scratch

typedef __attribute__((ext_vector_type(32))) float f32x32;
typedef __attribute__((ext_vector_type(8)))  short short8;
typedef __attribute__((ext_vector_type(4)))  float f32x4;

// ---------------------------------------------------------------------------
// reference-exact numpy reduction tree (proven absmax 0.0 in R1/R3-R13)
__device__ __forceinline__ float tree_dot(const f32x32& x, const f32x32& y) {
    float a[8];
#pragma unroll
    for (int j = 0; j < 8; ++j) a[j] = x[j] * y[j];
#pragma unroll
    for (int j = 8; j < RVQ_D; ++j) a[j & 7] = fmaf(x[j], y[j], a[j & 7]);
    return ((a[0] + a[1]) + (a[2] + a[3])) + ((a[4] + a[5]) + (a[6] + a[7]));
}

__device__ __forceinline__ f32x32 st_update(const f32x32& r, const f32x32& gv) {
    const f32x32 tt  = gv - r;
    const f32x32 qst = r + tt;
    return r - qst;
}

__device__ __forceinline__ short8 as_s8(uint4 u) {
    union { uint4 a; short8 b; } x; x.a = u; return x.b;
}
__device__ __forceinline__ unsigned pk_hi(float v0, float v1) {
    return (__float_as_uint(v0) >> 16) | (__float_as_uint(v1) & 0xFFFF0000u);
}
__device__ __forceinline__ float lo_rem(float v) {
    return v - __uint_as_float(__float_as_uint(v) & 0xFFFF0000u);
}
__device__ __forceinline__ unsigned pack_mm(float m1, float m2) {
    const unsigned a = __half_as_ushort(__float2half_rd(m1));
    const unsigned b = __half_as_ushort(__float2half_rd(m2));
    return a | (b << 16);
}
__device__ __forceinline__ float unpk_lo(unsigned u) {
    return __half2float(__ushort_as_half((unsigned short)(u & 0xFFFFu)));
}
__device__ __forceinline__ float unpk_hi(unsigned u) {
    return __half2float(__ushort_as_half((unsigned short)(u >> 16)));
}

// ---------------------------------------------------------------------------
// Kernel P: codebook -> bf16 hi/lo MFMA fragments + exact norms (once/call).
// Fragment bit-pattern identical to R13's cfrag staging (validated).
__global__ __launch_bounds__(64) void rvq_prep(const float* __restrict__ cb,
                                               uint4* __restrict__ scb,
                                               float* __restrict__ normg) {
    const int cnd = blockIdx.x * 64 + threadIdx.x;       // 0..5119
    const f32x32 c = *(const f32x32*)(cb + (long)cnd * RVQ_D);
    normg[cnd] = tree_dot(c, c);
    const int q = cnd >> 9, cq = cnd & 511, ct = cq >> 4, col = cq & 15;
    const long base = (long)(q * 32 + ct) * 128 + col;
#pragma unroll
    for (int g = 0; g < 4; ++g)
#pragma unroll
        for (int sp = 0; sp < 2; ++sp) {
            unsigned u[4];
#pragma unroll
            for (int pr = 0; pr < 4; ++pr) {
                const int j = g * 8 + pr * 2;
                float v0 = c[j], v1 = c[j + 1];
                if (sp == 1) { v0 = lo_rem(v0); v1 = lo_rem(v1); }
                u[pr] = pk_hi(v0, v1);
            }
            scb[base + (g * 2 + sp) * 16] = make_uint4(u[0], u[1], u[2], u[3]);
        }
}

// ---------------------------------------------------------------------------
// Kernel S: search. ONE wave per block, 64 points. No __syncthreads anywhere.
__global__ __launch_bounds__(64, 2) void rvq_search(const float* __restrict__ z,
                                                    const float* __restrict__ cb,
                                                    const uint4* __restrict__ scb,
                                                    const float* __restrict__ normg,
                                                    float* __restrict__ iout) {
    __shared__ uint4 ptfrag[BPTS * 8];            // 8 KB point bf16 splits (-2r)
    __shared__ float snorm_l[RVQ_C];              // 2 KB exact norms (stage)
    __shared__ float rrbuf[BPTS];                 // 256 B
    __shared__ unsigned classmm[BPTS * 17];       // 4.25 KB
    __shared__ unsigned short classid[BPTS * 16]; // 2 KB

    const int t    = threadIdx.x;          // 0..63 == lane
    const int col  = t & 15;
    const int g    = t >> 4;
    const int sw0  = g ^ (col & 7);
    const int sw1  = (4 + g) ^ (col & 7);
    const long p   = (long)blockIdx.x * BPTS + t;

    f32x32 r = *(const f32x32*)(z + p * RVQ_D);

#pragma unroll 1
    for (int q = 0; q < RVQ_Q; ++q) {
        const float* cbq  = cb + (long)q * RVQ_C * RVQ_D;
        const uint4* scbq = scb + (long)q * 4096;

        // ---- stage norms -> LDS + ccmax (wave-internal, no barrier)
        float ccm = 0.0f;
#pragma unroll
        for (int n = 0; n < 8; ++n) {
            const float v = normg[q * RVQ_C + t + 64 * n];
            snorm_l[t + 64 * n] = v;
            ccm = fmaxf(ccm, v);
        }
#pragma unroll
        for (int m_ = 1; m_ <= 32; m_ <<= 1) ccm = fmaxf(ccm, __shfl_xor(ccm, m_, 64));

        // ---- E phase: rr, -2r bf16 split -> ptfrag (same bit-pattern as R13)
        const float rr = tree_dot(r, r);
        rrbuf[t] = rr;
        {
            const f32x32 s = -2.0f * r;
#pragma unroll
            for (int sp = 0; sp < 2; ++sp)
#pragma unroll
                for (int gg = 0; gg < 4; ++gg) {
                    unsigned u[4];
#pragma unroll
                    for (int pr = 0; pr < 4; ++pr) {
                        const int j = gg * 8 + pr * 2;
                        float v0 = s[j], v1 = s[j + 1];
                        if (sp == 1) { v0 = lo_rem(v0); v1 = lo_rem(v1); }
                        u[pr] = pk_hi(v0, v1);
                    }
                    ptfrag[t * 8 + ((sp * 4 + gg) ^ (t & 7))] =
                        make_uint4(u[0], u[1], u[2], u[3]);
                }
        }

        // ---- hoist A fragments + rr rows (registers for whole sweep)
        uint4 ahr[4], alr[4];
        float rr4[4][4];
#pragma unroll
        for (int TL = 0; TL < 4; ++TL) {
            ahr[TL] = ptfrag[(TL * 16 + col) * 8 + sw0];
            alr[TL] = ptfrag[(TL * 16 + col) * 8 + sw1];
#pragma unroll
            for (int i = 0; i < 4; ++i) rr4[TL][i] = rrbuf[TL * 16 + 4 * g + i];
        }

        // ---- trackers
        float m1[4][4], m2[4][4];
        int   idr[4][4];
#pragma unroll
        for (int a = 0; a < 4; ++a)
#pragma unroll
            for (int b = 0; b < 4; ++b) {
                m1[a][b] = __builtin_inff(); m2[a][b] = __builtin_inff();
                idr[a][b] = 0;
            }

        // ---- sweep: candidate fragments streamed from L2, zero barriers
#pragma unroll 2
        for (int ct = 0; ct < 32; ++ct) {
            const uint4 bhv = scbq[ct * 128 + g * 32 + col];
            const uint4 blv = scbq[ct * 128 + g * 32 + col + 16];
            const short8 bh = as_s8(bhv);
            const short8 bl = as_s8(blv);
            const float ccv = snorm_l[ct * 16 + col];
            const int   cnd = ct * 16 + col;
#pragma unroll
            for (int TL = 0; TL < 4; ++TL) {
                const short8 ah = as_s8(ahr[TL]);
                const short8 al = as_s8(alr[TL]);
                f32x4 acc = {rr4[TL][0] + ccv, rr4[TL][1] + ccv,
                             rr4[TL][2] + ccv, rr4[TL][3] + ccv};
                acc = __builtin_amdgcn_mfma_f32_16x16x32_bf16(ah, bh, acc, 0, 0, 0);
                acc = __builtin_amdgcn_mfma_f32_16x16x32_bf16(al, bh, acc, 0, 0, 0);
                acc = __builtin_amdgcn_mfma_f32_16x16x32_bf16(ah, bl, acc, 0, 0, 0);
#pragma unroll
                for (int i = 0; i < 4; ++i) {
                    const float v = acc[i];
                    const bool lt = v < m1[TL][i];
                    m2[TL][i]  = lt ? m1[TL][i] : fminf(m2[TL][i], v);
                    idr[TL][i] = lt ? cnd : idr[TL][i];
                    m1[TL][i]  = lt ? v : m1[TL][i];
                }
            }
        }

        // ---- publish trackers (wave-internal LDS)
#pragma unroll
        for (int TL = 0; TL < 4; ++TL)
#pragma unroll
            for (int i = 0; i < 4; ++i) {
                const int pt = TL * 16 + 4 * g + i;
                classmm[pt * 17 + col] = pack_mm(m1[TL][i], m2[TL][i]);
                classid[pt * 16 + col] = (unsigned short)idr[TL][i];
            }

        // ---- R phase (R13-proven): exact eval of admitted class argmins
        {
            float mm = __builtin_inff();
#pragma unroll
            for (int c = 0; c < 16; ++c) mm = fminf(mm, unpk_lo(classmm[t * 17 + c]));
            const float thr = mm + (rr + ccm) * 0.001953125f;   // 2^-9

            float bd = __builtin_inff(); int bi = 0;
            auto evalExact = [&](int cnd) {
                const f32x32 cvv = *(const f32x32*)(cbq + (long)cnd * RVQ_D);
                const float d = fmaf(-2.0f, tree_dot(r, cvv), rr) + snorm_l[cnd];
                if (d < bd || (d == bd && cnd < bi)) { bd = d; bi = cnd; }
            };
#pragma unroll 1
            for (int c = 0; c < 16; ++c) {
                const unsigned u = classmm[t * 17 + c];
                if (unpk_lo(u) <= thr) {
                    if (unpk_hi(u) <= thr) {
#pragma unroll 1
                        for (int kk = 0; kk < 32; ++kk) evalExact(kk * 16 + c);
                    } else {
                        evalExact((int)classid[t * 16 + c]);
                    }
                }
            }
            iout[p * RVQ_Q + q] = (float)bi;
            const f32x32 gw = *(const f32x32*)(cbq + (long)bi * RVQ_D);
            r = st_update(r, gw);
        }
    }
}

// ---------------------------------------------------------------------------
// Replay: bit-exact straight-through chain from stored indices (proven
// pre+post-timing R3-R13). Overwrites the scratch region with quantized.
__global__ __launch_bounds__(256) void rvq_replay(const float* __restrict__ z,
                                                  const float* __restrict__ cb,
                                                  float* __restrict__ out) {
    const int p = blockIdx.x * 256 + threadIdx.x;

    float r[RVQ_D], oacc[RVQ_D];
    {
        const float4* zp = (const float4*)(z + (long)p * RVQ_D);
#pragma unroll
        for (int w = 0; w < 8; ++w) {
            const float4 v = zp[w];
            r[w * 4 + 0] = v.x; r[w * 4 + 1] = v.y;
            r[w * 4 + 2] = v.z; r[w * 4 + 3] = v.w;
        }
    }
#pragma unroll
    for (int d = 0; d < RVQ_D; ++d) oacc[d] = 0.0f;

#pragma unroll 1
    for (int q = 0; q < RVQ_Q; ++q) {
        const int idx = (int)out[IDX_OFF + (long)p * RVQ_Q + q];
        const float4* cwb = (const float4*)(cb + ((long)q * RVQ_C + idx) * RVQ_D);
        float cwv[RVQ_D];
#pragma unroll
        for (int w = 0; w < 8; ++w) {
            const float4 v = cwb[w];
            cwv[w * 4 + 0] = v.x; cwv[w * 4 + 1] = v.y;
            cwv[w * 4 + 2] = v.z; cwv[w * 4 + 3] = v.w;
        }
#pragma unroll
        for (int d = 0; d < RVQ_D; ++d) {
            const float qst = r[d] + (cwv[d] - r[d]);
            oacc[d] += qst;
            r[d] = r[d] - qst;
        }
    }

    float4* qo = (float4*)(out + (long)p * RVQ_D);
#pragma unroll
    for (int w = 0; w < 8; ++w) {
        float4 v;
        v.x = oacc[w * 4 + 0]; v.y = oacc[w * 4 + 1];
        v.z = oacc[w * 4 + 2]; v.w = oacc[w * 4 + 3];
        qo[w] = v;
    }

    if (p < RVQ_Q) out[LOSS_OFF + p] = 0.0f;
}

// ---------------------------------------------------------------------------
extern "C" void kernel_launch(void* const* d_in, const int* in_sizes, int n_in,
                              void* d_out, int out_size, void* d_ws, size_t ws_size,
                              hipStream_t stream) {
    const float* z  = (const float*)d_in[0];
    const float* cb = (const float*)d_in[1];
    float* out = (float*)d_out;
    (void)d_ws; (void)ws_size;   // no workspace (R6 lesson)

    // scratch inside the quantized region (rewritten every call; replay
    // overwrites it at the end — R4/R5-proven pattern)
    uint4* scb   = (uint4*)out;                 // 655 KB fragments
    float* normg = out + NORM_OFF;              // 5120 exact norms
    float* iout  = out + IDX_OFF;

    rvq_prep  <<<(RVQ_Q * RVQ_C) / 64, 64, 0, stream>>>(cb, scb, normg);
    rvq_search<<<NPTS / BPTS, BPTS, 0, stream>>>(z, cb, scb, normg, iout);
    rvq_replay<<<NPTS / 256, 256, 0, stream>>>(z, cb, out);
}

// Round 15
// 512.261 us; speedup vs baseline: 8.9384x; 1.3634x over previous
//
#include <hip/hip_runtime.h>
#include <hip/hip_fp16.h>

// Residual VQ on MI355X (gfx950) — MFMA distance engine, barrier-free,
// packed-key tracker + wave-cooperative exact rescue.
// z: [8, 32768, 32] f32; codebooks: [10, 512, 32] f32.
// Outputs (flat f32 in d_out): quantized [B,N,D], indices [B,N,Q] (as float),
// commit_loss [Q] (zeros).
//
// R15 = R14 (prep-converted codebook fragments, 1-wave blocks, zero barriers,
// per-class m1/m2 + thr=(rr+ccm)*2^-9 exact rescue — absmax 0.0, 698 us)
// with the two measured VALU hogs fixed:
//  (1) tracker: d3 biased positive (biasW=(rrmax+ccm)*2^-9 folded into MFMA
//      C-init) then key=(bits(v)&~511)|cnd via v_and_or; m1/m2 via u32
//      min/max — 4 VALU/value (was 5-6 + separate id cndmask). u32-trunc
//      (2^-14) is strictly tighter than R14's passing fp16-rd (2^-11);
//      round-down direction (over-admit) preserved.
//  (2) R-phase full-class scans made WAVE-COOPERATIVE: ballot the points
//      whose m2 <= thr, broadcast their residual via shfl, 32 lanes eval
//      the class in parallel + (d,cnd) reduce — removes the divergent-union
//      cost that dominated R14's VALU.
// All exact math (numpy tree, ST chain), MFMA split bit-pattern, delta, and
// prep/replay kernels are bit-identical to the proven R14.

#define RVQ_Q 10
#define RVQ_C 512
#define RVQ_D 32

static constexpr int  NPTS      = 262144;
static constexpr long IDX_OFF   = (long)NPTS * RVQ_D;
static constexpr long LOSS_OFF  = IDX_OFF + (long)NPTS * RVQ_Q;
static constexpr int  BPTS      = 64;            // points per block (1 wave)
static constexpr int  SCB_U4    = RVQ_Q * 32 * 8 * 16;   // 40960 uint4
static constexpr long NORM_OFF  = (long)SCB_U4 * 4;      // floats into scratch
static constexpr unsigned KMASK = 0xFFFFFE00u;   // drop 9 bits for cnd

typedef __attribute__((ext_vector_type(32))) float f32x32;
typedef __attribute__((ext_vector_type(8)))  short short8;
typedef __attribute__((ext_vector_type(4)))  float f32x4;

// ---------------------------------------------------------------------------
// reference-exact numpy reduction tree (proven absmax 0.0 in R1/R3-R14)
__device__ __forceinline__ float tree_dot(const f32x32& x, const f32x32& y) {
    float a[8];
#pragma unroll
    for (int j = 0; j < 8; ++j) a[j] = x[j] * y[j];
#pragma unroll
    for (int j = 8; j < RVQ_D; ++j) a[j & 7] = fmaf(x[j], y[j], a[j & 7]);
    return ((a[0] + a[1]) + (a[2] + a[3])) + ((a[4] + a[5]) + (a[6] + a[7]));
}

__device__ __forceinline__ f32x32 st_update(const f32x32& r, const f32x32& gv) {
    const f32x32 tt  = gv - r;
    const f32x32 qst = r + tt;
    return r - qst;
}

__device__ __forceinline__ short8 as_s8(uint4 u) {
    union { uint4 a; short8 b; } x; x.a = u; return x.b;
}
__device__ __forceinline__ unsigned pk_hi(float v0, float v1) {
    return (__float_as_uint(v0) >> 16) | (__float_as_uint(v1) & 0xFFFF0000u);
}
__device__ __forceinline__ float lo_rem(float v) {
    return v - __uint_as_float(__float_as_uint(v) & 0xFFFF0000u);
}
__device__ __forceinline__ unsigned umn(unsigned a, unsigned b) { return a < b ? a : b; }
__device__ __forceinline__ unsigned umx(unsigned a, unsigned b) { return a > b ? a : b; }

// ---------------------------------------------------------------------------
// Kernel P: codebook -> bf16 hi/lo MFMA fragments + exact norms (R14-proven).
__global__ __launch_bounds__(64) void rvq_prep(const float* __restrict__ cb,
                                               uint4* __restrict__ scb,
                                               float* __restrict__ normg) {
    const int cnd = blockIdx.x * 64 + threadIdx.x;       // 0..5119
    const f32x32 c = *(const f32x32*)(cb + (long)cnd * RVQ_D);
    normg[cnd] = tree_dot(c, c);
    const int q = cnd >> 9, cq = cnd & 511, ct = cq >> 4, col = cq & 15;
    const long base = (long)(q * 32 + ct) * 128 + col;
#pragma unroll
    for (int g = 0; g < 4; ++g)
#pragma unroll
        for (int sp = 0; sp < 2; ++sp) {
            unsigned u[4];
#pragma unroll
            for (int pr = 0; pr < 4; ++pr) {
                const int j = g * 8 + pr * 2;
                float v0 = c[j], v1 = c[j + 1];
                if (sp == 1) { v0 = lo_rem(v0); v1 = lo_rem(v1); }
                u[pr] = pk_hi(v0, v1);
            }
            scb[base + (g * 2 + sp) * 16] = make_uint4(u[0], u[1], u[2], u[3]);
        }
}

// ---------------------------------------------------------------------------
// Kernel S: search. ONE wave per block, 64 points, no __syncthreads.
__global__ __launch_bounds__(64, 2) void rvq_search(const float* __restrict__ z,
                                                    const float* __restrict__ cb,
                                                    const uint4* __restrict__ scb,
                                                    const float* __restrict__ normg,
                                                    float* __restrict__ iout) {
    __shared__ uint4 ptfrag[BPTS * 8];            // 8 KB point bf16 splits (-2r)
    __shared__ float snorm_l[RVQ_C];              // 2 KB exact norms
    __shared__ float rrbuf[BPTS];                 // 256 B
    __shared__ unsigned m1key_s[BPTS * 17];       // 4.25 KB
    __shared__ unsigned short m2h_s[BPTS * 17];   // 2.1 KB

    const int t    = threadIdx.x;          // 0..63 == lane
    const int col  = t & 15;
    const int g    = t >> 4;
    const int sw0  = g ^ (col & 7);
    const int sw1  = (4 + g) ^ (col & 7);
    const long p   = (long)blockIdx.x * BPTS + t;

    f32x32 r = *(const f32x32*)(z + p * RVQ_D);

#pragma unroll 1
    for (int q = 0; q < RVQ_Q; ++q) {
        const float* cbq  = cb + (long)q * RVQ_C * RVQ_D;
        const uint4* scbq = scb + (long)q * 4096;

        // ---- norms -> LDS + ccm (wave max), rr + rrmax (wave max)
        float ccm = 0.0f;
#pragma unroll
        for (int n = 0; n < 8; ++n) {
            const float v = normg[q * RVQ_C + t + 64 * n];
            snorm_l[t + 64 * n] = v;
            ccm = fmaxf(ccm, v);
        }
#pragma unroll
        for (int m_ = 1; m_ <= 32; m_ <<= 1) ccm = fmaxf(ccm, __shfl_xor(ccm, m_, 64));

        const float rr = tree_dot(r, r);
        rrbuf[t] = rr;
        float rrmax = rr;
#pragma unroll
        for (int m_ = 1; m_ <= 32; m_ <<= 1) rrmax = fmaxf(rrmax, __shfl_xor(rrmax, m_, 64));
        const float biasW = (rrmax + ccm) * 0.001953125f;   // 2^-9, >= err bound

        // ---- E phase: -2r bf16 split -> ptfrag (R14-proven bit-pattern)
        {
            const f32x32 s = -2.0f * r;
#pragma unroll
            for (int sp = 0; sp < 2; ++sp)
#pragma unroll
                for (int gg = 0; gg < 4; ++gg) {
                    unsigned u[4];
#pragma unroll
                    for (int pr = 0; pr < 4; ++pr) {
                        const int j = gg * 8 + pr * 2;
                        float v0 = s[j], v1 = s[j + 1];
                        if (sp == 1) { v0 = lo_rem(v0); v1 = lo_rem(v1); }
                        u[pr] = pk_hi(v0, v1);
                    }
                    ptfrag[t * 8 + ((sp * 4 + gg) ^ (t & 7))] =
                        make_uint4(u[0], u[1], u[2], u[3]);
                }
        }

        // ---- hoist A fragments + biased rr rows
        uint4 ahr[4], alr[4];
        float rrb4[4][4];
#pragma unroll
        for (int TL = 0; TL < 4; ++TL) {
            ahr[TL] = ptfrag[(TL * 16 + col) * 8 + sw0];
            alr[TL] = ptfrag[(TL * 16 + col) * 8 + sw1];
#pragma unroll
            for (int i = 0; i < 4; ++i)
                rrb4[TL][i] = rrbuf[TL * 16 + 4 * g + i] + biasW;
        }

        // ---- packed-key trackers
        unsigned m1k[4][4], m2k[4][4];
#pragma unroll
        for (int a = 0; a < 4; ++a)
#pragma unroll
            for (int b = 0; b < 4; ++b) { m1k[a][b] = 0xFFFFFFFFu; m2k[a][b] = 0xFFFFFFFFu; }

        int cndv = col;   // candidate id of this lane's column, += 16 per ct

        // ---- sweep: candidate fragments streamed from L2, zero barriers
#pragma unroll 2
        for (int ct = 0; ct < 32; ++ct) {
            const short8 bh = as_s8(scbq[ct * 128 + g * 32 + col]);
            const short8 bl = as_s8(scbq[ct * 128 + g * 32 + col + 16]);
            const float ccv = snorm_l[ct * 16 + col];
#pragma unroll
            for (int TL = 0; TL < 4; ++TL) {
                const short8 ah = as_s8(ahr[TL]);
                const short8 al = as_s8(alr[TL]);
                f32x4 acc = {rrb4[TL][0] + ccv, rrb4[TL][1] + ccv,
                             rrb4[TL][2] + ccv, rrb4[TL][3] + ccv};
                acc = __builtin_amdgcn_mfma_f32_16x16x32_bf16(ah, bh, acc, 0, 0, 0);
                acc = __builtin_amdgcn_mfma_f32_16x16x32_bf16(al, bh, acc, 0, 0, 0);
                acc = __builtin_amdgcn_mfma_f32_16x16x32_bf16(ah, bl, acc, 0, 0, 0);
#pragma unroll
                for (int i = 0; i < 4; ++i) {
                    const unsigned key = (__float_as_uint(acc[i]) & KMASK) | (unsigned)cndv;
                    m2k[TL][i] = umn(m2k[TL][i], umx(m1k[TL][i], key));
                    m1k[TL][i] = umn(m1k[TL][i], key);
                }
            }
            cndv += 16;
        }

        // ---- publish trackers (wave-internal LDS)
#pragma unroll
        for (int TL = 0; TL < 4; ++TL)
#pragma unroll
            for (int i = 0; i < 4; ++i) {
                const int pt = TL * 16 + 4 * g + i;
                m1key_s[pt * 17 + col] = m1k[TL][i];
                const float m2f = __uint_as_float(m2k[TL][i] & KMASK);
                m2h_s[pt * 17 + col] = __half_as_ushort(__float2half_rd(m2f));
            }

        // ---- R phase: admitted-id evals (SIMT) + wave-cooperative scans
        float bd = __builtin_inff(); int bi = 0;
        unsigned smask = 0;
        {
            unsigned mmk = 0xFFFFFFFFu;
#pragma unroll
            for (int c = 0; c < 16; ++c) mmk = umn(mmk, m1key_s[t * 17 + c]);
            const float thrf = __uint_as_float(mmk & KMASK) + (rr + ccm) * 0.001953125f;

            auto evalExact = [&](int cnd) {
                const f32x32 cvv = *(const f32x32*)(cbq + (long)cnd * RVQ_D);
                const float d = fmaf(-2.0f, tree_dot(r, cvv), rr) + snorm_l[cnd];
                if (d < bd || (d == bd && cnd < bi)) { bd = d; bi = cnd; }
            };
#pragma unroll 1
            for (int c = 0; c < 16; ++c) {
                const unsigned k1 = m1key_s[t * 17 + c];
                const bool adm = __uint_as_float(k1 & KMASK) <= thrf;
                const bool scn = __half2float(__ushort_as_half(m2h_s[t * 17 + c])) <= thrf;
                smask |= (scn ? 1u : 0u) << c;
                if (adm && !scn) evalExact((int)(k1 & 511u));
            }

            // cooperative full-class scans (rare; ~110 instr/request)
            unsigned long long bal = __ballot(smask != 0);
            const int l31 = t & 31;
            while (bal) {
                const int b = (int)__builtin_ctzll(bal); bal &= bal - 1;
                unsigned sm = (unsigned)__shfl((int)smask, b, 64);
                f32x32 rb;
#pragma unroll
                for (int j = 0; j < RVQ_D; ++j) rb[j] = __shfl(r[j], b, 64);
                const float rrb = __shfl(rr, b, 64);
                while (sm) {
                    const int c = (int)__builtin_ctz(sm); sm &= sm - 1;
                    int  ci = l31 * 16 + c;
                    const f32x32 cvv = *(const f32x32*)(cbq + (long)ci * RVQ_D);
                    float d = fmaf(-2.0f, tree_dot(rb, cvv), rrb) + snorm_l[ci];
#pragma unroll
                    for (int m_ = 1; m_ <= 32; m_ <<= 1) {
                        const float od = __shfl_xor(d, m_, 64);
                        const int   oi = __shfl_xor(ci, m_, 64);
                        if (od < d || (od == d && oi < ci)) { d = od; ci = oi; }
                    }
                    if (t == b) {
                        if (d < bd || (d == bd && ci < bi)) { bd = d; bi = ci; }
                    }
                }
            }
        }

        iout[p * RVQ_Q + q] = (float)bi;
        const f32x32 gw = *(const f32x32*)(cbq + (long)bi * RVQ_D);
        r = st_update(r, gw);
    }
}

// ---------------------------------------------------------------------------
// Replay: bit-exact straight-through chain from stored indices (proven
// pre+post-timing R3-R14). Overwrites the scratch region with quantized.
__global__ __launch_bounds__(256) void rvq_replay(const float* __restrict__ z,
                                                  const float* __restrict__ cb,
                                                  float* __restrict__ out) {
    const int p = blockIdx.x * 256 + threadIdx.x;

    float r[RVQ_D], oacc[RVQ_D];
    {
        const float4* zp = (const float4*)(z + (long)p * RVQ_D);
#pragma unroll
        for (int w = 0; w < 8; ++w) {
            const float4 v = zp[w];
            r[w * 4 + 0] = v.x; r[w * 4 + 1] = v.y;
            r[w * 4 + 2] = v.z; r[w * 4 + 3] = v.w;
        }
    }
#pragma unroll
    for (int d = 0; d < RVQ_D; ++d) oacc[d] = 0.0f;

#pragma unroll 1
    for (int q = 0; q < RVQ_Q; ++q) {
        const int idx = (int)out[IDX_OFF + (long)p * RVQ_Q + q];
        const float4* cwb = (const float4*)(cb + ((long)q * RVQ_C + idx) * RVQ_D);
        float cwv[RVQ_D];
#pragma unroll
        for (int w = 0; w < 8; ++w) {
            const float4 v = cwb[w];
            cwv[w * 4 + 0] = v.x; cwv[w * 4 + 1] = v.y;
            cwv[w * 4 + 2] = v.z; cwv[w * 4 + 3] = v.w;
        }
#pragma unroll
        for (int d = 0; d < RVQ_D; ++d) {
            const float qst = r[d] + (cwv[d] - r[d]);
            oacc[d] += qst;
            r[d] = r[d] - qst;
        }
    }

    float4* qo = (float4*)(out + (long)p * RVQ_D);
#pragma unroll
    for (int w = 0; w < 8; ++w) {
        float4 v;
        v.x = oacc[w * 4 + 0]; v.y = oacc[w * 4 + 1];
        v.z = oacc[w * 4 + 2]; v.w = oacc[w * 4 + 3];
        qo[w] = v;
    }

    if (p < RVQ_Q) out[LOSS_OFF + p] = 0.0f;
}

// ---------------------------------------------------------------------------
extern "C" void kernel_launch(void* const* d_in, const int* in_sizes, int n_in,
                              void* d_out, int out_size, void* d_ws, size_t ws_size,
                              hipStream_t stream) {
    const float* z  = (const float*)d_in[0];
    const float* cb = (const float*)d_in[1];
    float* out = (float*)d_out;
    (void)d_ws; (void)ws_size;   // no workspace (R6 lesson)

    // scratch inside the quantized region (rewritten every call; replay
    // overwrites it at the end — R4/R5/R14-proven pattern)
    uint4* scb   = (uint4*)out;                 // 655 KB fragments
    float* normg = out + NORM_OFF;              // 5120 exact norms
    float* iout  = out + IDX_OFF;

    rvq_prep  <<<(RVQ_Q * RVQ_C) / 64, 64, 0, stream>>>(cb, scb, normg);
    rvq_search<<<NPTS / BPTS, BPTS, 0, stream>>>(z, cb, scb, normg, iout);
    rvq_replay<<<NPTS / 256, 256, 0, stream>>>(z, cb, out);
}